// Round 2
// baseline (6110.284 us; speedup 1.0000x reference)
//
#include <hip/hip_runtime.h>
#include <hip/hip_bf16.h>

typedef __hip_bfloat16 bf16;
typedef __bf16 bf16x8 __attribute__((ext_vector_type(8)));
typedef float f32x4v __attribute__((ext_vector_type(4)));

#define B_ 64
#define H_ 512
#define E_ 512
#define L_ 3
#define V_ 32000
#define S_ 64
#define ML_ 64
#define EH_ 1024

// fp32 W_gen -> bf16 (once per launch; generator GEMM runs on MFMA)
__global__ void cast_wg(const float* __restrict__ src, bf16* __restrict__ dst, int n4) {
  int i = blockIdx.x * blockDim.x + threadIdx.x;
  if (i < n4) {
    float4 v = reinterpret_cast<const float4*>(src)[i];
    union { bf16 h[4]; uint2 u; } o;
    o.h[0] = __float2bfloat16(v.x); o.h[1] = __float2bfloat16(v.y);
    o.h[2] = __float2bfloat16(v.z); o.h[3] = __float2bfloat16(v.w);
    reinterpret_cast<uint2*>(dst)[i] = o.u;
  }
}

// Per-batch block: token embed -> attn logits -> softmax -> context.
// Writes a2g[b] = [e (512) | context (512)]
__global__ void attn_a(const int* __restrict__ cur, const int* __restrict__ gtr, int t,
                       const float* __restrict__ emb, const float* __restrict__ Wa,
                       const float* __restrict__ enc, const float* __restrict__ h2,
                       float* __restrict__ a2g) {
  __shared__ float a_in[EH_];
  __shared__ float red[256];
  __shared__ float w[ML_];
  const int b = blockIdx.x, tid = threadIdx.x;
  const int token = (t == 0) ? cur[b] : gtr[(t - 1) * B_ + b];
  const float* e = emb + (size_t)token * E_;
  for (int i = tid; i < E_; i += 256) { float v = e[i]; a_in[i] = v; a2g[b * EH_ + i] = v; }
  for (int i = tid; i < H_; i += 256) a_in[E_ + i] = h2[b * H_ + i];
  __syncthreads();
  { // logits partials: row s = tid>>2, quarter q = tid&3
    const int s = tid >> 2, q = tid & 3;
    const float4* wr = reinterpret_cast<const float4*>(Wa + (size_t)s * EH_ + q * 256);
    const float* ap = a_in + q * 256;
    float p = 0.f;
#pragma unroll 8
    for (int ii = 0; ii < 64; ++ii) {
      float4 wv = wr[ii];
      p += wv.x * ap[ii * 4] + wv.y * ap[ii * 4 + 1] + wv.z * ap[ii * 4 + 2] + wv.w * ap[ii * 4 + 3];
    }
    red[tid] = p;
  }
  __syncthreads();
  if (tid < ML_) { // softmax over full MAXLEN in wave 0
    float v = red[4 * tid] + red[4 * tid + 1] + red[4 * tid + 2] + red[4 * tid + 3];
    float m = v;
#pragma unroll
    for (int off = 32; off; off >>= 1) m = fmaxf(m, __shfl_xor(m, off));
    float ex = expf(v - m), ss = ex;
#pragma unroll
    for (int off = 32; off; off >>= 1) ss += __shfl_xor(ss, off);
    w[tid] = ex / ss;
  }
  __syncthreads();
  for (int hh = tid; hh < H_; hh += 256) { // context
    float acc = 0.f;
#pragma unroll 8
    for (int s = 0; s < S_; ++s) acc += w[s] * enc[((size_t)s * B_ + b) * H_ + hh];
    a2g[b * EH_ + E_ + hh] = acc;
  }
}

// x = relu(a2 @ Wao^T): grid (32 output-blocks of 16, 4 batch-groups of 16)
__global__ void attn_gemm(const float* __restrict__ a2g, const float* __restrict__ Wao,
                          float* __restrict__ x_out) {
  __shared__ float a2s[16 * 516];
  const int bx = blockIdx.x, bg = blockIdx.y, tid = threadIdx.x;
  const int b = tid & 15, o = tid >> 4;
  const int j = bx * 16 + o;
  float acc = 0.f;
  for (int kh = 0; kh < 2; ++kh) {
    __syncthreads();
#pragma unroll
    for (int c = 0; c < 8; ++c) { // stage 16 rows x 512 cols
      int f = c * 256 + tid;
      int row = f >> 7, c4 = f & 127;
      *reinterpret_cast<float4*>(a2s + row * 516 + c4 * 4) =
          *reinterpret_cast<const float4*>(a2g + (size_t)(bg * 16 + row) * EH_ + kh * 512 + c4 * 4);
    }
    __syncthreads();
    const float4* wr = reinterpret_cast<const float4*>(Wao + (size_t)j * EH_ + kh * 512);
    const float* ap = a2s + b * 516;
#pragma unroll 8
    for (int kq = 0; kq < 128; ++kq) {
      float4 wv = wr[kq];
      float4 av = *reinterpret_cast<const float4*>(ap + kq * 4);
      acc += wv.x * av.x + wv.y * av.y + wv.z * av.z + wv.w * av.w;
    }
  }
  x_out[(size_t)(bg * 16 + b) * E_ + j] = fmaxf(acc, 0.f);
}

// One LSTM layer step. grid (128 neuron-blocks of 4, 4 batch-groups of 16).
// Block computes 16 gate-outputs (4 neurons x 4 gates) for 16 batches, then
// fuses the LSTM pointwise in-block.
__global__ void lstm_gates(const float* __restrict__ Wih, const float* __restrict__ Whh,
                           const float* __restrict__ bih, const float* __restrict__ bhh,
                           const float* __restrict__ x_in, const float* __restrict__ h_prev,
                           const float* __restrict__ c_prev,
                           float* __restrict__ h_out, float* __restrict__ c_out,
                           bf16* __restrict__ xg) {
  __shared__ float sbuf[16 * 516];
  __shared__ float gsm[16][17];
  const int bx = blockIdx.x, bg = blockIdx.y, tid = threadIdx.x;
  const int b = tid & 15, o = tid >> 4;
  const int g = o >> 2, dn = o & 3;
  const int n = bx * 4 + dn;
  const int j = g * H_ + n;
  float acc = bih[j] + bhh[j];
  // --- x @ Wih^T ---
#pragma unroll
  for (int c = 0; c < 8; ++c) {
    int f = c * 256 + tid;
    int row = f >> 7, c4 = f & 127;
    *reinterpret_cast<float4*>(sbuf + row * 516 + c4 * 4) =
        *reinterpret_cast<const float4*>(x_in + (size_t)(bg * 16 + row) * H_ + c4 * 4);
  }
  __syncthreads();
  {
    const float4* wr = reinterpret_cast<const float4*>(Wih + (size_t)j * H_);
    const float* ap = sbuf + b * 516;
#pragma unroll 8
    for (int kq = 0; kq < 128; ++kq) {
      float4 wv = wr[kq];
      float4 av = *reinterpret_cast<const float4*>(ap + kq * 4);
      acc += wv.x * av.x + wv.y * av.y + wv.z * av.z + wv.w * av.w;
    }
  }
  __syncthreads();
  // --- h_prev @ Whh^T (reuse sbuf) ---
#pragma unroll
  for (int c = 0; c < 8; ++c) {
    int f = c * 256 + tid;
    int row = f >> 7, c4 = f & 127;
    *reinterpret_cast<float4*>(sbuf + row * 516 + c4 * 4) =
        *reinterpret_cast<const float4*>(h_prev + (size_t)(bg * 16 + row) * H_ + c4 * 4);
  }
  __syncthreads();
  {
    const float4* wr = reinterpret_cast<const float4*>(Whh + (size_t)j * H_);
    const float* ap = sbuf + b * 516;
#pragma unroll 8
    for (int kq = 0; kq < 128; ++kq) {
      float4 wv = wr[kq];
      float4 av = *reinterpret_cast<const float4*>(ap + kq * 4);
      acc += wv.x * av.x + wv.y * av.y + wv.z * av.z + wv.w * av.w;
    }
  }
  gsm[b][o] = acc;
  __syncthreads();
  if (tid < 64) { // fused pointwise: 16 batches x 4 neurons
    const int bb = tid & 15, d2 = tid >> 4;
    const int nn = bx * 4 + d2;
    const int bg2 = bg * 16 + bb;
    const float ig = 1.f / (1.f + expf(-gsm[bb][d2]));
    const float fg = 1.f / (1.f + expf(-gsm[bb][4 + d2]));
    const float gc = tanhf(gsm[bb][8 + d2]);
    const float og = 1.f / (1.f + expf(-gsm[bb][12 + d2]));
    const float cv = fg * c_prev[(size_t)bg2 * H_ + nn] + ig * gc;
    const float hv = og * tanhf(cv);
    c_out[(size_t)bg2 * H_ + nn] = cv;
    h_out[(size_t)bg2 * H_ + nn] = hv;
    if (xg) xg[(size_t)bg2 * H_ + nn] = __float2bfloat16(hv);
  }
}

// C[M,V] fp32 = A[M,512] bf16 @ Wg[V,512]^T bf16 + bg; 64x64 tile, 16x16x32 MFMA
__global__ void gen_gemm(const bf16* __restrict__ A, const bf16* __restrict__ Wg,
                         const float* __restrict__ bg, float* __restrict__ C) {
  constexpr int K = H_;
  __shared__ __align__(16) bf16 Asm[64 * 32];
  __shared__ __align__(16) bf16 Bsm[64 * 32];
  const int mb = blockIdx.x, nb = blockIdx.y;  // mb fastest: 50 blocks share one Wg tile
  const int tid = threadIdx.x;
  const int wave = tid >> 6, lane = tid & 63;
  const int qm = lane >> 4, ml = lane & 15;
  f32x4v acc[4];
#pragma unroll
  for (int i = 0; i < 4; ++i) acc[i] = {0.f, 0.f, 0.f, 0.f};
  const int r = tid >> 2, ck = tid & 3;
  const bf16* Ar = A + ((size_t)(mb * 64 + r)) * K + ck * 8;
  const bf16* Br = Wg + ((size_t)(nb * 64 + r)) * K + ck * 8;
  for (int k0 = 0; k0 < K; k0 += 32) {
    __syncthreads();
    *reinterpret_cast<uint4*>(&Asm[r * 32 + ck * 8]) = *reinterpret_cast<const uint4*>(Ar + k0);
    *reinterpret_cast<uint4*>(&Bsm[r * 32 + ck * 8]) = *reinterpret_cast<const uint4*>(Br + k0);
    __syncthreads();
    bf16x8 af = *reinterpret_cast<const bf16x8*>(&Asm[(wave * 16 + ml) * 32 + qm * 8]);
#pragma unroll
    for (int tn = 0; tn < 4; ++tn) {
      bf16x8 bfv = *reinterpret_cast<const bf16x8*>(&Bsm[(tn * 16 + ml) * 32 + qm * 8]);
      acc[tn] = __builtin_amdgcn_mfma_f32_16x16x32_bf16(af, bfv, acc[tn], 0, 0, 0);
    }
  }
  // C/D: col = lane&15, row = (lane>>4)*4 + reg
#pragma unroll
  for (int tn = 0; tn < 4; ++tn) {
    const int gcol = nb * 64 + tn * 16 + ml;
    const float bias = bg[gcol];
#pragma unroll
    for (int rr = 0; rr < 4; ++rr) {
      const int grow = mb * 64 + wave * 16 + qm * 4 + rr;
      C[(size_t)grow * V_ + gcol] = acc[tn][rr] + bias;
    }
  }
}

// in-place fp32 log_softmax over each row of [M, V]
__global__ void log_softmax_rows(float* __restrict__ out) {
  __shared__ float wred[4], wsum[4];
  const size_t row = blockIdx.x;
  float* p = out + row * V_;
  const int tid = threadIdx.x;
  float m = -3.4e38f;
  for (int i = tid; i < V_; i += 256) m = fmaxf(m, p[i]);
#pragma unroll
  for (int off = 32; off; off >>= 1) m = fmaxf(m, __shfl_xor(m, off));
  if ((tid & 63) == 0) wred[tid >> 6] = m;
  __syncthreads();
  m = fmaxf(fmaxf(wred[0], wred[1]), fmaxf(wred[2], wred[3]));
  float s = 0.f;
  for (int i = tid; i < V_; i += 256) s += expf(p[i] - m);
#pragma unroll
  for (int off = 32; off; off >>= 1) s += __shfl_xor(s, off);
  if ((tid & 63) == 0) wsum[tid >> 6] = s;
  __syncthreads();
  const float lse = m + logf(wsum[0] + wsum[1] + wsum[2] + wsum[3]);
  for (int i = tid; i < V_; i += 256) p[i] = p[i] - lse;
}

extern "C" void kernel_launch(void* const* d_in, const int* in_sizes, int n_in,
                              void* d_out, int out_size, void* d_ws, size_t ws_size,
                              hipStream_t stream) {
  (void)n_in; (void)out_size; (void)ws_size;
  const int*   cur = (const int*)d_in[0];
  const float* hid_h = (const float*)d_in[1];
  const float* hid_c = (const float*)d_in[2];
  const float* enc = (const float*)d_in[4];
  const int*   gtr = (const int*)d_in[5];
  const float* emb = (const float*)d_in[6];
  const float* Wa  = (const float*)d_in[7];
  const float* Wao = (const float*)d_in[8];
  const float* Wih = (const float*)d_in[9];
  const float* Whh = (const float*)d_in[10];
  const float* bih = (const float*)d_in[11];
  const float* bhh = (const float*)d_in[12];
  const float* Wg  = (const float*)d_in[13];
  const float* bg  = (const float*)d_in[14];
  const int T = in_sizes[5] / B_;  // 50
  const int nstate = L_ * B_ * H_;

  // ws layout (fp32 then bf16): ~38 MB
  float* wsf    = (float*)d_ws;
  float* hbuf   = wsf;                        // [2][L][B][H]
  float* cbuf   = hbuf + 2 * nstate;          // [2][L][B][H]
  float* a2g    = cbuf + 2 * nstate;          // [B][EH]
  float* x_attn = a2g + B_ * EH_;             // [B][E]
  bf16*  x_gen  = (bf16*)(x_attn + B_ * E_);  // [T][B][H] bf16
  bf16*  wg_b   = x_gen + (size_t)T * B_ * H_;// [V][H] bf16

  cast_wg<<<dim3(V_ * H_ / 4 / 256), dim3(256), 0, stream>>>(Wg, wg_b, V_ * H_ / 4);
  hipMemcpyAsync(hbuf, hid_h, (size_t)nstate * 4, hipMemcpyDeviceToDevice, stream);
  hipMemcpyAsync(cbuf, hid_c, (size_t)nstate * 4, hipMemcpyDeviceToDevice, stream);

  int curb = 0;
  for (int t = 0; t < T; ++t) {
    float* hsrc = hbuf + curb * nstate;
    float* csrc = cbuf + curb * nstate;
    float* hdst = hbuf + (1 - curb) * nstate;
    float* cdst = cbuf + (1 - curb) * nstate;
    attn_a<<<dim3(B_), dim3(256), 0, stream>>>(cur, gtr, t, emb, Wa, enc,
                                               hsrc + 2 * B_ * H_, a2g);
    attn_gemm<<<dim3(E_ / 16, 4), dim3(256), 0, stream>>>(a2g, Wao, x_attn);
    for (int l = 0; l < L_; ++l) {
      const float* x_in = (l == 0) ? x_attn : (hdst + (l - 1) * B_ * H_);
      bf16* xg = (l == 2) ? (x_gen + (size_t)t * B_ * H_) : nullptr;
      lstm_gates<<<dim3(H_ / 4, 4), dim3(256), 0, stream>>>(
          Wih + (size_t)l * 4 * H_ * E_, Whh + (size_t)l * 4 * H_ * H_,
          bih + l * 4 * H_, bhh + l * 4 * H_,
          x_in, hsrc + l * B_ * H_, csrc + l * B_ * H_,
          hdst + l * B_ * H_, cdst + l * B_ * H_, xg);
    }
    curb = 1 - curb;
  }

  float* out = (float*)d_out;
  const int M = T * B_;  // 3200
  gen_gemm<<<dim3(M / 64, V_ / 64), dim3(256), 0, stream>>>(x_gen, wg_b, bg, out);
  log_softmax_rows<<<dim3(M), dim3(256), 0, stream>>>(out);
  float* outh = out + (size_t)M * V_;
  hipMemcpyAsync(outh, hbuf + curb * nstate, (size_t)nstate * 4, hipMemcpyDeviceToDevice, stream);
  hipMemcpyAsync(outh + nstate, cbuf + curb * nstate, (size_t)nstate * 4, hipMemcpyDeviceToDevice, stream);
}